// Round 5
// baseline (313.642 us; speedup 1.0000x reference)
//
#include <hip/hip_runtime.h>
#include <hip/hip_bf16.h>
#include <stdint.h>

// Problem constants
#define DIMS  2048
#define HEADS 16
#define HD    128
#define BATCH 2
#define SEQ   2048
#define MROWS (BATCH*SEQ)   // 4096
#define QKVN  (3*DIMS)      // 6144

using bf16x8 = __attribute__((ext_vector_type(8))) short;
using f32x4  = __attribute__((ext_vector_type(4))) float;
using f32x16 = __attribute__((ext_vector_type(16))) float;
using u16x4  = __attribute__((ext_vector_type(4))) unsigned short;

__device__ __forceinline__ unsigned short f2b(float f){
    __hip_bfloat16 h = __float2bfloat16(f);
    return *reinterpret_cast<unsigned short*>(&h);
}
__device__ __forceinline__ float b2f(unsigned short u){
    __hip_bfloat16 h;
    *reinterpret_cast<unsigned short*>(&h) = u;
    return __bfloat162float(h);
}
__device__ __forceinline__ unsigned int pkbf(float lo, float hi){
    return (unsigned int)f2b(lo) | ((unsigned int)f2b(hi) << 16);
}

// async global->LDS, 16B per lane. LDS dest is wave-uniform base (+lane*16 implicit).
__device__ __forceinline__ void glds16(const void* g, void* l){
    __builtin_amdgcn_global_load_lds(
        (const __attribute__((address_space(1))) unsigned int*)g,
        (__attribute__((address_space(3))) unsigned int*)l, 16, 0, 0);
}

// ---------------- elementwise prep kernels ----------------

__global__ void k_f32bf16(const float* __restrict__ src, unsigned short* __restrict__ dst, int n4){
    int i = blockIdx.x*blockDim.x + threadIdx.x;
    if (i >= n4) return;
    const float4 v = reinterpret_cast<const float4*>(src)[i];
    u16x4 o = { f2b(v.x), f2b(v.y), f2b(v.z), f2b(v.w) };
    *reinterpret_cast<u16x4*>(dst + 4*(size_t)i) = o;
}

__global__ void k_cossin(const float* __restrict__ r, float* __restrict__ c, float* __restrict__ s, int n){
    int i = blockIdx.x*blockDim.x + threadIdx.x;
    if (i >= n) return;
    float v = r[i];
    c[i] = cosf(v);
    s[i] = sinf(v);
}

// RoPE in-place on Q and K sections of qkv [MROWS][6144] bf16
__global__ void k_rope(unsigned short* __restrict__ qkv,
                       const float* __restrict__ ct, const float* __restrict__ st){
    const int idx = blockIdx.x*blockDim.x + threadIdx.x;
    const int d = idx & 63;
    const int h = (idx >> 6) & (HEADS-1);
    const int l = (idx >> 10) & (SEQ-1);
    const int b = idx >> 21;
    const float c0 = ct[l*HD + d],      s0 = st[l*HD + d];
    const float c1 = ct[l*HD + d + 64], s1 = st[l*HD + d + 64];
    unsigned short* row = qkv + (size_t)(b*SEQ + l)*QKVN + h*HD;
    {   // Q
        float x1 = b2f(row[d]), x2 = b2f(row[d+64]);
        row[d]    = f2b(x1*c0 - x2*s0);
        row[d+64] = f2b(x2*c1 + x1*s1);
    }
    {   // K
        unsigned short* kr = row + DIMS;
        float x1 = b2f(kr[d]), x2 = b2f(kr[d+64]);
        kr[d]    = f2b(x1*c0 - x2*s0);
        kr[d+64] = f2b(x2*c1 + x1*s1);
    }
}

// V transpose: qkv V section [b][l][h*128+d] -> vt[(b*16+h)*128 + d][l]
__global__ void k_vtrans(const unsigned short* __restrict__ qkv, unsigned short* __restrict__ vt){
    __shared__ unsigned short t[64*68];
    const int lt = blockIdx.x;
    const int dt = blockIdx.y;
    const int bh = blockIdx.z;
    const int b = bh >> 4, h = bh & 15;
    const int tid = threadIdx.x;
    const int l0 = lt << 6;
    #pragma unroll
    for (int it = 0; it < 4; ++it){
        const int c = tid + (it<<8);
        const int l = c >> 4;
        const int d4 = (c & 15) << 2;
        const u16x4 v = *reinterpret_cast<const u16x4*>(
            qkv + (size_t)(b*SEQ + l0 + l)*QKVN + 2*DIMS + h*HD + (dt<<6) + d4);
        *reinterpret_cast<u16x4*>(&t[l*68 + d4]) = v;
    }
    __syncthreads();
    #pragma unroll
    for (int it = 0; it < 4; ++it){
        const int c = tid + (it<<8);
        const int d = c >> 4;
        const int l4 = (c & 15) << 2;
        u16x4 o = { t[(l4+0)*68 + d], t[(l4+1)*68 + d], t[(l4+2)*68 + d], t[(l4+3)*68 + d] };
        *reinterpret_cast<u16x4*>(&vt[((size_t)bh*HD + (dt<<6) + d)*SEQ + l0 + l4]) = o;
    }
}

// ---------------- 256x128 2-phase counted-vmcnt GEMM ----------------
// C[M][N] = A[M][K] * B[N][K]^T. BK=64. 8 waves: wm=wave>>2 (2 row-bands of 64 per
// 128-row half), wn=wave&3 (4 col-bands of 32). Per-wave output 128x32.
// Grid: (M/256)*(N/128). QKV: 16*48=768 = exactly 3 rounds of 256 CUs.
//       out-proj: 16*16=256 = exactly 1 round.
// LDS 96 KiB: lA[parity][half][128*64], lB[parity][128*64], XOR-swizzled
// (chunk ^= row&7) via pre-swizzled global source.
//
// Per K-tile t (parity p=t&1): P0 reads A-half0 + B (full rows), stages A1(t+1)
// [other parity, always safe]. P1 reads A-half1, stages A0(t+2)+B(t+2) [parity p;
// those regions' last read was P0, whose trailing barrier has passed]. vmcnt(4)
// at tile end drains everything through A1(t+1) (issue order ...A0(t),B(t),A1(t),
// A0(t+1),B(t+1) -> keep newest 4 loads = A0(t+1),B(t+1)... shifted by one tile:
// entering tile t, in flight = A0(t+1),B(t+1)? No: invariant = {A0,B}(t+1) issued
// at t-1's P1 still in flight (4 loads); during t: +A1(t+1) +{A0,B}(t+2) = 10;
// vmcnt(4) leaves {A0,B}(t+2), so A1(t+1) and earlier landed. Tail: vmcnt(0) for
// t >= nkt-2. Prologue: tile0 {A0,B,A1} + tile1 {A0,B} = 10 loads; vmcnt(4) =>
// tile0 landed.

__device__ __forceinline__ void stg128(const unsigned short* __restrict__ src, int row0, int k0,
                                       unsigned short* dstregion, int wave, int lane, int Kld){
    #pragma unroll
    for (int i = 0; i < 2; ++i){
        const int r  = (i<<6) + (wave<<3) + (lane>>3);
        const int cc = (lane&7) ^ (r&7);
        glds16(src + (size_t)(row0 + r)*Kld + k0 + (cc<<3), dstregion + (((i<<6)+(wave<<3))<<6));
    }
}

template<int FINAL>
__global__ __launch_bounds__(512, 2) void k_gemm256b(
    const unsigned short* __restrict__ A, const unsigned short* __restrict__ B,
    void* __restrict__ C, const float* __restrict__ bias, int M, int N, int K)
{
    __shared__ unsigned short lA[2][2][128*64];   // [parity][half]
    __shared__ unsigned short lB[2][128*64];      // [parity]

    const int tid  = threadIdx.x;
    const int lane = tid & 63;
    const int wave = tid >> 6;
    const int wm   = wave >> 2;         // 0..1 : 64-row band within each 128-half
    const int wn   = wave & 3;          // 0..3 : 32-col band
    const int nkt  = K >> 6;

    const int nbx = N >> 7;
    const int nwg = gridDim.x;
    const int cpx = nwg >> 3;
    const int wg  = (blockIdx.x & 7)*cpx + (blockIdx.x >> 3);   // XCD swizzle (nwg%8==0)
    const int m0 = (wg / nbx) << 8;
    const int n0 = (wg % nbx) << 7;

    f32x4 acc[2][4][2] = {};            // [half][mi][ni]

#define ST_A(T, H) do{ if ((T) < nkt) stg128(A, m0 + ((H)<<7), (T)<<6, &lA[(T)&1][H][0], wave, lane, K); }while(0)
#define ST_B(T)    do{ if ((T) < nkt) stg128(B, n0,            (T)<<6, &lB[(T)&1][0],    wave, lane, K); }while(0)

#define RD_A(REG) do{ \
    _Pragma("unroll") for (int mi=0;mi<4;++mi) _Pragma("unroll") for (int ks=0;ks<2;++ks){ \
        const int rowh = (wm<<6) + (mi<<4) + (lane&15); \
        const int c8 = (ks<<2) + (lane>>4); \
        af[mi][ks] = *reinterpret_cast<const bf16x8*>(&(REG)[(rowh<<6) + ((c8 ^ (rowh&7))<<3)]); \
    } }while(0)
#define RD_B(REG) do{ \
    _Pragma("unroll") for (int ni=0;ni<2;++ni) _Pragma("unroll") for (int ks=0;ks<2;++ks){ \
        const int rowh = (wn<<5) + (ni<<4) + (lane&15); \
        const int c8 = (ks<<2) + (lane>>4); \
        bf[ni][ks] = *reinterpret_cast<const bf16x8*>(&(REG)[(rowh<<6) + ((c8 ^ (rowh&7))<<3)]); \
    } }while(0)

#define MM(H) do{ \
    __builtin_amdgcn_s_setprio(1); \
    _Pragma("unroll") for (int ks=0;ks<2;++ks) \
    _Pragma("unroll") for (int mi=0;mi<4;++mi) \
    _Pragma("unroll") for (int ni=0;ni<2;++ni) \
        acc[H][mi][ni] = __builtin_amdgcn_mfma_f32_16x16x32_bf16(af[mi][ks], bf[ni][ks], acc[H][mi][ni], 0,0,0); \
    __builtin_amdgcn_s_setprio(0); \
    }while(0)

    // ---- prologue: tile0 {A0,B,A1} + tile1 {A0,B}; vmcnt(4) => tile0 landed ----
    ST_A(0,0); ST_B(0); ST_A(0,1);
    ST_A(1,0); ST_B(1);
    asm volatile("s_waitcnt vmcnt(4)" ::: "memory");
    __builtin_amdgcn_s_barrier();
    __builtin_amdgcn_sched_barrier(0);

    for (int t = 0; t < nkt; ++t){
        const int p = t & 1;
        bf16x8 af[4][2], bf[2][2];

        // ---- P0: half0, B (b-frags carried to P1) ----
        RD_A(lA[p][0]);
        RD_B(lB[p]);
        ST_A(t+1, 1);
        __builtin_amdgcn_s_barrier();
        MM(0);
        __builtin_amdgcn_s_barrier();

        // ---- P1: half1 (A0/B regions of parity p are dead after P0's barrier) ----
        RD_A(lA[p][1]);
        ST_A(t+2, 0);
        ST_B(t+2);
        __builtin_amdgcn_s_barrier();
        MM(1);
        if (t + 2 < nkt) { asm volatile("s_waitcnt vmcnt(4)" ::: "memory"); }
        else             { asm volatile("s_waitcnt vmcnt(0)" ::: "memory"); }
        __builtin_amdgcn_s_barrier();
        __builtin_amdgcn_sched_barrier(0);
    }

#undef ST_A
#undef ST_B
#undef RD_A
#undef RD_B
#undef MM

    // ---- epilogue: D layout col=lane&15, row=(lane>>4)*4+rr ----
    const int r0 = (lane >> 4) << 2;
    const int cn = lane & 15;
    #pragma unroll
    for (int h = 0; h < 2; ++h)
      #pragma unroll
      for (int mi = 0; mi < 4; ++mi)
        #pragma unroll
        for (int rr = 0; rr < 4; ++rr){
            const int gm = m0 + (h<<7) + (wm<<6) + (mi<<4) + r0 + rr;
            #pragma unroll
            for (int ni = 0; ni < 2; ++ni){
                const int gn = n0 + (wn<<5) + (ni<<4) + cn;
                const float v = acc[h][mi][ni][rr];
                if (FINAL)
                    reinterpret_cast<float*>(C)[(size_t)gm*N + gn] = v + bias[gn];
                else
                    reinterpret_cast<unsigned short*>(C)[(size_t)gm*N + gn] = f2b(v);
            }
        }
}

// ---------------- flash attention, swapped-operand 32x32 structure ----------------

union U8 { unsigned int w[4]; bf16x8 v; };

__global__ __launch_bounds__(512, 2) void k_attn(
    const unsigned short* __restrict__ qkv, const unsigned short* __restrict__ vt,
    unsigned short* __restrict__ aout)
{
    __shared__ unsigned short lK[2][64*128];
    __shared__ unsigned short lV[2][128*64];
    __shared__ unsigned short lO[8*32*132];

    const int tid  = threadIdx.x;
    const int lane = tid & 63;
    const int wave = tid >> 6;
    const int lq   = lane & 31;
    const int hi   = lane >> 5;
    const int bh = blockIdx.y;
    const int b = bh >> 4, h = bh & 15;
    const int q0w = (blockIdx.x << 8) + (wave << 5);

    const unsigned short* Kb = qkv + (size_t)b*SEQ*QKVN + DIMS + h*HD;
    const unsigned short* Vb = vt + (size_t)bh*HD*SEQ;

    bf16x8 qf[8];
    {
        const float qscale = 0.08838834764831845f * 1.4426950408889634f;
        const unsigned short* qp = qkv + (size_t)(b*SEQ + q0w + lq)*QKVN + h*HD + (hi<<3);
        #pragma unroll
        for (int ks = 0; ks < 8; ++ks){
            bf16x8 tv = *reinterpret_cast<const bf16x8*>(qp + (ks<<4));
            #pragma unroll
            for (int j = 0; j < 8; ++j)
                tv[j] = (short)f2b(b2f((unsigned short)tv[j]) * qscale);
            qf[ks] = tv;
        }
    }

    float m_run = -3e38f, l_run = 0.f;
    f32x16 oacc[4] = {};

    #define STAGE(pb, kv0) do { \
        _Pragma("unroll") \
        for (int i = 0; i < 2; ++i){ \
            const int kr = (wave<<3) + (i<<2) + (lane>>4); \
            glds16(Kb + (size_t)((kv0) + kr)*QKVN + (((lane&15) ^ (kr&7))<<3), \
                   &lK[pb][((wave<<3) + (i<<2))<<7]); \
            const int dr = (wave<<4) + (i<<3) + (lane>>3); \
            glds16(Vb + (size_t)dr*SEQ + (kv0) + (((lane&7) ^ (dr&7))<<3), \
                   &lV[pb][((wave<<4) + (i<<3))<<6]); \
        } \
    } while(0)

    int buf = 0;
    STAGE(0, 0);
    __syncthreads();

    for (int t = 0; t < SEQ/64; ++t){
        if (t < SEQ/64 - 1) STAGE(buf^1, (t+1)*64);

        const unsigned short* Kbuf = &lK[buf][0];
        const unsigned short* Vbuf = &lV[buf][0];

        f32x16 st0 = {}, st1 = {};
        #pragma unroll
        for (int ks = 0; ks < 8; ++ks){
            const int col = (((ks<<1) + hi) ^ (lq & 7)) << 3;
            bf16x8 k0 = *reinterpret_cast<const bf16x8*>(&Kbuf[(lq<<7) + col]);
            bf16x8 k1 = *reinterpret_cast<const bf16x8*>(&Kbuf[((32+lq)<<7) + col]);
            st0 = __builtin_amdgcn_mfma_f32_32x32x16_bf16(k0, qf[ks], st0, 0, 0, 0);
            st1 = __builtin_amdgcn_mfma_f32_32x32x16_bf16(k1, qf[ks], st1, 0, 0, 0);
        }

        float tmax = st0[0];
        #pragma unroll
        for (int r = 1; r < 16; ++r) tmax = fmaxf(tmax, st0[r]);
        #pragma unroll
        for (int r = 0; r < 16; ++r) tmax = fmaxf(tmax, st1[r]);
        tmax = fmaxf(tmax, __shfl_xor(tmax, 32));
        const float mnew = fmaxf(m_run, tmax);
        const float al = __builtin_amdgcn_exp2f(m_run - mnew);
        m_run = mnew;
        float tsum = 0.f;
        #pragma unroll
        for (int r = 0; r < 16; ++r){ float p = __builtin_amdgcn_exp2f(st0[r] - mnew); st0[r] = p; tsum += p; }
        #pragma unroll
        for (int r = 0; r < 16; ++r){ float p = __builtin_amdgcn_exp2f(st1[r] - mnew); st1[r] = p; tsum += p; }
        tsum += __shfl_xor(tsum, 32);
        l_run = l_run*al + tsum;
        #pragma unroll
        for (int dt = 0; dt < 4; ++dt) oacc[dt] *= al;

        bf16x8 pf[4];
        #define MAKEPF(dA, dB, SV) do { \
            unsigned int a0 = pkbf(SV[0],SV[1]),  b0 = pkbf(SV[2],SV[3]); \
            unsigned int c0 = pkbf(SV[4],SV[5]),  d0 = pkbf(SV[6],SV[7]); \
            unsigned int a1 = pkbf(SV[8],SV[9]),  b1 = pkbf(SV[10],SV[11]); \
            unsigned int c1 = pkbf(SV[12],SV[13]),d1 = pkbf(SV[14],SV[15]); \
            unsigned int ax0 = __shfl_xor(a0,32), bx0 = __shfl_xor(b0,32); \
            unsigned int cx0 = __shfl_xor(c0,32), dx0 = __shfl_xor(d0,32); \
            unsigned int ax1 = __shfl_xor(a1,32), bx1 = __shfl_xor(b1,32); \
            unsigned int cx1 = __shfl_xor(c1,32), dx1 = __shfl_xor(d1,32); \
            U8 u; \
            u.w[0] = hi ? cx0 : a0;  u.w[1] = hi ? dx0 : b0; \
            u.w[2] = hi ? c0 : ax0;  u.w[3] = hi ? d0 : bx0; \
            dA = u.v; \
            u.w[0] = hi ? cx1 : a1;  u.w[1] = hi ? dx1 : b1; \
            u.w[2] = hi ? c1 : ax1;  u.w[3] = hi ? d1 : bx1; \
            dB = u.v; \
        } while(0)
        MAKEPF(pf[0], pf[1], st0);
        MAKEPF(pf[2], pf[3], st1);
        #undef MAKEPF

        #pragma unroll
        for (int dt = 0; dt < 4; ++dt){
            const int rowv = (dt<<5) + lq;
            #pragma unroll
            for (int f = 0; f < 4; ++f){
                const int col = (((f<<1) + hi) ^ (lq & 7)) << 3;
                bf16x8 vf = *reinterpret_cast<const bf16x8*>(&Vbuf[(rowv<<6) + col]);
                oacc[dt] = __builtin_amdgcn_mfma_f32_32x32x16_bf16(vf, pf[f], oacc[dt], 0, 0, 0);
            }
        }

        __syncthreads();
        buf ^= 1;
    }
    #undef STAGE

    const float rl = 1.0f / l_run;
    unsigned short* oL = lO + wave*(32*132);
    #pragma unroll
    for (int dt = 0; dt < 4; ++dt)
        #pragma unroll
        for (int g = 0; g < 4; ++g){
            u16x4 w = { f2b(oacc[dt][g*4+0]*rl), f2b(oacc[dt][g*4+1]*rl),
                        f2b(oacc[dt][g*4+2]*rl), f2b(oacc[dt][g*4+3]*rl) };
            *reinterpret_cast<u16x4*>(&oL[lq*132 + (dt<<5) + (hi<<2) + (g<<3)]) = w;
        }
    #pragma unroll
    for (int i = 0; i < 16; ++i){
        const int q = (i<<1) + hi;
        u16x4 w = *reinterpret_cast<const u16x4*>(&oL[q*132 + (lq<<2)]);
        *reinterpret_cast<u16x4*>(&aout[(size_t)(b*SEQ + q0w + q)*DIMS + h*HD + (lq<<2)]) = w;
    }
}

// ---------------- launcher ----------------

extern "C" void kernel_launch(void* const* d_in, const int* in_sizes, int n_in,
                              void* d_out, int out_size, void* d_ws, size_t ws_size,
                              hipStream_t stream)
{
    const float* x    = (const float*)d_in[0];
    const float* rope = (const float*)d_in[1];
    const float* wq   = (const float*)d_in[2];
    const float* wk   = (const float*)d_in[3];
    const float* wv   = (const float*)d_in[4];
    const float* wo   = (const float*)d_in[5];
    const float* bo   = (const float*)d_in[6];
    float* out = (float*)d_out;

    char* ws = (char*)d_ws;
    unsigned short* x_bf   = (unsigned short*)(ws + 0);            // 16.8 MB
    unsigned short* wqkv   = (unsigned short*)(ws + 16777216);     // 25.2 MB
    unsigned short* wo_bf  = (unsigned short*)(ws + 41943040);     // 8.4 MB
    float*          cos_t  = (float*)(ws + 50331648);              // 1 MB
    float*          sin_t  = (float*)(ws + 51380224);              // 1 MB
    unsigned short* qkv    = (unsigned short*)(ws + 52428800);     // 50.3 MB
    unsigned short* vt     = (unsigned short*)(ws + 16777216);     // alias wqkv
    unsigned short* a_out  = (unsigned short*)(ws + 0);            // alias x_bf

    k_f32bf16<<<8192, 256, 0, stream>>>(x,  x_bf,              2097152);
    k_f32bf16<<<4096, 256, 0, stream>>>(wq, wqkv,              1048576);
    k_f32bf16<<<4096, 256, 0, stream>>>(wk, wqkv + 4194304,    1048576);
    k_f32bf16<<<4096, 256, 0, stream>>>(wv, wqkv + 8388608,    1048576);
    k_f32bf16<<<4096, 256, 0, stream>>>(wo, wo_bf,             1048576);
    k_cossin <<<1024, 256, 0, stream>>>(rope, cos_t, sin_t, SEQ*HD);

    // QKV projection: 256x128 tile -> grid 16*48 = 768 blocks = exactly 3 rounds
    k_gemm256b<0><<<(MROWS/256)*(QKVN/128), 512, 0, stream>>>(x_bf, wqkv, qkv, nullptr, MROWS, QKVN, DIMS);

    k_rope<<<16384, 256, 0, stream>>>(qkv, cos_t, sin_t);

    k_vtrans<<<dim3(SEQ/64, HD/64, BATCH*HEADS), 256, 0, stream>>>(qkv, vt);

    k_attn<<<dim3(SEQ/256, BATCH*HEADS), 512, 0, stream>>>(qkv, vt, a_out);

    // output projection + bias: grid 16*16 = 256 blocks = exactly 1 round
    k_gemm256b<1><<<(MROWS/256)*(DIMS/128), 512, 0, stream>>>(a_out, wo_bf, out, bo, MROWS, DIMS, DIMS);
}

// Round 6
// 305.738 us; speedup vs baseline: 1.0259x; 1.0259x over previous
//
#include <hip/hip_runtime.h>
#include <hip/hip_bf16.h>
#include <stdint.h>

// Problem constants
#define DIMS  2048
#define HEADS 16
#define HD    128
#define BATCH 2
#define SEQ   2048
#define MROWS (BATCH*SEQ)   // 4096
#define QKVN  (3*DIMS)      // 6144

using bf16x8 = __attribute__((ext_vector_type(8))) short;
using f32x4  = __attribute__((ext_vector_type(4))) float;
using f32x16 = __attribute__((ext_vector_type(16))) float;
using u16x4  = __attribute__((ext_vector_type(4))) unsigned short;

__device__ __forceinline__ unsigned short f2b(float f){
    __hip_bfloat16 h = __float2bfloat16(f);
    return *reinterpret_cast<unsigned short*>(&h);
}
__device__ __forceinline__ float b2f(unsigned short u){
    __hip_bfloat16 h;
    *reinterpret_cast<unsigned short*>(&h) = u;
    return __bfloat162float(h);
}
__device__ __forceinline__ unsigned int pkbf(float lo, float hi){
    return (unsigned int)f2b(lo) | ((unsigned int)f2b(hi) << 16);
}

// async global->LDS, 16B per lane. LDS dest is wave-uniform base (+lane*16 implicit).
__device__ __forceinline__ void glds16(const void* g, void* l){
    __builtin_amdgcn_global_load_lds(
        (const __attribute__((address_space(1))) unsigned int*)g,
        (__attribute__((address_space(3))) unsigned int*)l, 16, 0, 0);
}

// ---------------- elementwise prep kernels ----------------

__global__ void k_f32bf16(const float* __restrict__ src, unsigned short* __restrict__ dst, int n4){
    int i = blockIdx.x*blockDim.x + threadIdx.x;
    if (i >= n4) return;
    const float4 v = reinterpret_cast<const float4*>(src)[i];
    u16x4 o = { f2b(v.x), f2b(v.y), f2b(v.z), f2b(v.w) };
    *reinterpret_cast<u16x4*>(dst + 4*(size_t)i) = o;
}

__global__ void k_cossin(const float* __restrict__ r, float* __restrict__ c, float* __restrict__ s, int n){
    int i = blockIdx.x*blockDim.x + threadIdx.x;
    if (i >= n) return;
    float v = r[i];
    c[i] = cosf(v);
    s[i] = sinf(v);
}

// RoPE in-place on Q and K sections of qkv [MROWS][6144] bf16 — vectorized bf16x8.
// thread: one (b,l,h, d-octet): d0=(idx&7)*8 covers d0..d0+8 and the paired d0+64..+72.
__global__ void k_rope(unsigned short* __restrict__ qkv,
                       const float* __restrict__ ct, const float* __restrict__ st){
    const int idx = blockIdx.x*blockDim.x + threadIdx.x;   // B*SEQ*HEADS*8 = 524288
    const int d0 = (idx & 7) << 3;
    const int h  = (idx >> 3) & (HEADS-1);
    const int l  = (idx >> 7) & (SEQ-1);
    const int b  = idx >> 18;

    const float4* cp = reinterpret_cast<const float4*>(ct + l*HD + d0);
    const float4* sp = reinterpret_cast<const float4*>(st + l*HD + d0);
    const float4 cl0 = cp[0],  cl1 = cp[1];
    const float4 sl0 = sp[0],  sl1 = sp[1];
    const float4 cu0 = cp[16], cu1 = cp[17];   // +64 floats
    const float4 su0 = sp[16], su1 = sp[17];
    const float cl[8] = {cl0.x,cl0.y,cl0.z,cl0.w, cl1.x,cl1.y,cl1.z,cl1.w};
    const float sl[8] = {sl0.x,sl0.y,sl0.z,sl0.w, sl1.x,sl1.y,sl1.z,sl1.w};
    const float cu[8] = {cu0.x,cu0.y,cu0.z,cu0.w, cu1.x,cu1.y,cu1.z,cu1.w};
    const float su[8] = {su0.x,su0.y,su0.z,su0.w, su1.x,su1.y,su1.z,su1.w};

    unsigned short* base = qkv + (size_t)(b*SEQ + l)*QKVN + h*HD + d0;
    #pragma unroll
    for (int s = 0; s < 2; ++s){               // s=0: Q, s=1: K
        unsigned short* rp = base + s*DIMS;
        bf16x8 lo = *reinterpret_cast<const bf16x8*>(rp);
        bf16x8 hi = *reinterpret_cast<const bf16x8*>(rp + 64);
        bf16x8 olo, ohi;
        #pragma unroll
        for (int j = 0; j < 8; ++j){
            const float x1 = b2f((unsigned short)lo[j]);
            const float x2 = b2f((unsigned short)hi[j]);
            olo[j] = (short)f2b(x1*cl[j] - x2*sl[j]);
            ohi[j] = (short)f2b(x2*cu[j] + x1*su[j]);
        }
        *reinterpret_cast<bf16x8*>(rp)      = olo;
        *reinterpret_cast<bf16x8*>(rp + 64) = ohi;
    }
}

// V transpose: qkv V section [b][l][h*128+d] -> vt[(b*16+h)*128 + d][l]
__global__ void k_vtrans(const unsigned short* __restrict__ qkv, unsigned short* __restrict__ vt){
    __shared__ unsigned short t[64*68];
    const int lt = blockIdx.x;
    const int dt = blockIdx.y;
    const int bh = blockIdx.z;
    const int b = bh >> 4, h = bh & 15;
    const int tid = threadIdx.x;
    const int l0 = lt << 6;
    #pragma unroll
    for (int it = 0; it < 4; ++it){
        const int c = tid + (it<<8);
        const int l = c >> 4;
        const int d4 = (c & 15) << 2;
        const u16x4 v = *reinterpret_cast<const u16x4*>(
            qkv + (size_t)(b*SEQ + l0 + l)*QKVN + 2*DIMS + h*HD + (dt<<6) + d4);
        *reinterpret_cast<u16x4*>(&t[l*68 + d4]) = v;
    }
    __syncthreads();
    #pragma unroll
    for (int it = 0; it < 4; ++it){
        const int c = tid + (it<<8);
        const int d = c >> 4;
        const int l4 = (c & 15) << 2;
        u16x4 o = { t[(l4+0)*68 + d], t[(l4+1)*68 + d], t[(l4+2)*68 + d], t[(l4+3)*68 + d] };
        *reinterpret_cast<u16x4*>(&vt[((size_t)bh*HD + (dt<<6) + d)*SEQ + l0 + l4]) = o;
    }
}

// ---------------- 128x128 GEMM (m97 structure) — both projections ----------------

template<int FINAL>
__global__ __launch_bounds__(256) void k_gemm_bt(
    const unsigned short* __restrict__ A, const unsigned short* __restrict__ B,
    void* __restrict__ C, const float* __restrict__ bias, int M, int N, int K)
{
    __shared__ unsigned short lA[128*64];
    __shared__ unsigned short lB[128*64];
    const int tid  = threadIdx.x;
    const int lane = tid & 63;
    const int wave = tid >> 6;

    const int nbx = N >> 7;
    const int nwg = gridDim.x;
    const int cpx = nwg >> 3;
    const int bid = blockIdx.x;
    const int wg  = (bid & 7)*cpx + (bid >> 3);
    const int m0 = (wg / nbx) << 7;
    const int n0 = (wg % nbx) << 7;

    const int wr = (wave >> 1) << 6;
    const int wc = (wave & 1) << 6;

    f32x4 acc[4][4] = {};

    const int srow_base = (wave<<3) + (lane>>3);
    const int schunk = lane & 7;

    for (int k0 = 0; k0 < K; k0 += 64){
        #pragma unroll
        for (int i = 0; i < 4; ++i){
            const int row  = (i<<5) + srow_base;
            const int scol = k0 + ((schunk ^ (row & 7)) << 3);
            glds16(A + (size_t)(m0 + row)*K + scol, &lA[((i<<5) + (wave<<3)) << 6]);
            glds16(B + (size_t)(n0 + row)*K + scol, &lB[((i<<5) + (wave<<3)) << 6]);
        }
        __syncthreads();
        #pragma unroll
        for (int ks = 0; ks < 2; ++ks){
            bf16x8 af[4], bfr[4];
            const int colbase = (ks<<5) + ((lane>>4)<<3);
            #pragma unroll
            for (int mi = 0; mi < 4; ++mi){
                const int row = wr + (mi<<4) + (lane & 15);
                af[mi] = *reinterpret_cast<const bf16x8*>(&lA[(row<<6) + (colbase ^ ((row&7)<<3))]);
            }
            #pragma unroll
            for (int ni = 0; ni < 4; ++ni){
                const int row = wc + (ni<<4) + (lane & 15);
                bfr[ni] = *reinterpret_cast<const bf16x8*>(&lB[(row<<6) + (colbase ^ ((row&7)<<3))]);
            }
            #pragma unroll
            for (int mi = 0; mi < 4; ++mi)
                #pragma unroll
                for (int ni = 0; ni < 4; ++ni)
                    acc[mi][ni] = __builtin_amdgcn_mfma_f32_16x16x32_bf16(af[mi], bfr[ni], acc[mi][ni], 0, 0, 0);
        }
        __syncthreads();
    }

    const int r0 = (lane >> 4) << 2;
    const int cn = lane & 15;
    #pragma unroll
    for (int mi = 0; mi < 4; ++mi)
        #pragma unroll
        for (int r = 0; r < 4; ++r){
            const int gm = m0 + wr + (mi<<4) + r0 + r;
            #pragma unroll
            for (int ni = 0; ni < 4; ++ni){
                const int gn = n0 + wc + (ni<<4) + cn;
                const float v = acc[mi][ni][r];
                if (FINAL)
                    reinterpret_cast<float*>(C)[(size_t)gm*N + gn] = v + bias[gn];
                else
                    reinterpret_cast<unsigned short*>(C)[(size_t)gm*N + gn] = f2b(v);
            }
        }
}

// ---------------- flash attention, swapped-operand 32x32 structure ----------------

union U8 { unsigned int w[4]; bf16x8 v; };

__global__ __launch_bounds__(512, 2) void k_attn(
    const unsigned short* __restrict__ qkv, const unsigned short* __restrict__ vt,
    unsigned short* __restrict__ aout)
{
    __shared__ unsigned short lK[2][64*128];
    __shared__ unsigned short lV[2][128*64];
    __shared__ unsigned short lO[8*32*132];

    const int tid  = threadIdx.x;
    const int lane = tid & 63;
    const int wave = tid >> 6;
    const int lq   = lane & 31;
    const int hi   = lane >> 5;
    const int bh = blockIdx.y;
    const int b = bh >> 4, h = bh & 15;
    const int q0w = (blockIdx.x << 8) + (wave << 5);

    const unsigned short* Kb = qkv + (size_t)b*SEQ*QKVN + DIMS + h*HD;
    const unsigned short* Vb = vt + (size_t)bh*HD*SEQ;

    bf16x8 qf[8];
    {
        const float qscale = 0.08838834764831845f * 1.4426950408889634f;
        const unsigned short* qp = qkv + (size_t)(b*SEQ + q0w + lq)*QKVN + h*HD + (hi<<3);
        #pragma unroll
        for (int ks = 0; ks < 8; ++ks){
            bf16x8 tv = *reinterpret_cast<const bf16x8*>(qp + (ks<<4));
            #pragma unroll
            for (int j = 0; j < 8; ++j)
                tv[j] = (short)f2b(b2f((unsigned short)tv[j]) * qscale);
            qf[ks] = tv;
        }
    }

    float m_run = -3e38f, l_run = 0.f;
    f32x16 oacc[4] = {};

    #define STAGE(pb, kv0) do { \
        _Pragma("unroll") \
        for (int i = 0; i < 2; ++i){ \
            const int kr = (wave<<3) + (i<<2) + (lane>>4); \
            glds16(Kb + (size_t)((kv0) + kr)*QKVN + (((lane&15) ^ (kr&7))<<3), \
                   &lK[pb][((wave<<3) + (i<<2))<<7]); \
            const int dr = (wave<<4) + (i<<3) + (lane>>3); \
            glds16(Vb + (size_t)dr*SEQ + (kv0) + (((lane&7) ^ (dr&7))<<3), \
                   &lV[pb][((wave<<4) + (i<<3))<<6]); \
        } \
    } while(0)

    int buf = 0;
    STAGE(0, 0);
    __syncthreads();

    for (int t = 0; t < SEQ/64; ++t){
        if (t < SEQ/64 - 1) STAGE(buf^1, (t+1)*64);

        const unsigned short* Kbuf = &lK[buf][0];
        const unsigned short* Vbuf = &lV[buf][0];

        f32x16 st0 = {}, st1 = {};
        __builtin_amdgcn_s_setprio(1);
        #pragma unroll
        for (int ks = 0; ks < 8; ++ks){
            const int col = (((ks<<1) + hi) ^ (lq & 7)) << 3;
            bf16x8 k0 = *reinterpret_cast<const bf16x8*>(&Kbuf[(lq<<7) + col]);
            bf16x8 k1 = *reinterpret_cast<const bf16x8*>(&Kbuf[((32+lq)<<7) + col]);
            st0 = __builtin_amdgcn_mfma_f32_32x32x16_bf16(k0, qf[ks], st0, 0, 0, 0);
            st1 = __builtin_amdgcn_mfma_f32_32x32x16_bf16(k1, qf[ks], st1, 0, 0, 0);
        }
        __builtin_amdgcn_s_setprio(0);

        float tmax = st0[0];
        #pragma unroll
        for (int r = 1; r < 16; ++r) tmax = fmaxf(tmax, st0[r]);
        #pragma unroll
        for (int r = 0; r < 16; ++r) tmax = fmaxf(tmax, st1[r]);
        tmax = fmaxf(tmax, __shfl_xor(tmax, 32));
        const float mnew = fmaxf(m_run, tmax);
        const float al = __builtin_amdgcn_exp2f(m_run - mnew);
        m_run = mnew;
        float tsum = 0.f;
        #pragma unroll
        for (int r = 0; r < 16; ++r){ float p = __builtin_amdgcn_exp2f(st0[r] - mnew); st0[r] = p; tsum += p; }
        #pragma unroll
        for (int r = 0; r < 16; ++r){ float p = __builtin_amdgcn_exp2f(st1[r] - mnew); st1[r] = p; tsum += p; }
        tsum += __shfl_xor(tsum, 32);
        l_run = l_run*al + tsum;
        #pragma unroll
        for (int dt = 0; dt < 4; ++dt) oacc[dt] *= al;

        bf16x8 pf[4];
        #define MAKEPF(dA, dB, SV) do { \
            unsigned int a0 = pkbf(SV[0],SV[1]),  b0 = pkbf(SV[2],SV[3]); \
            unsigned int c0 = pkbf(SV[4],SV[5]),  d0 = pkbf(SV[6],SV[7]); \
            unsigned int a1 = pkbf(SV[8],SV[9]),  b1 = pkbf(SV[10],SV[11]); \
            unsigned int c1 = pkbf(SV[12],SV[13]),d1 = pkbf(SV[14],SV[15]); \
            unsigned int ax0 = __shfl_xor(a0,32), bx0 = __shfl_xor(b0,32); \
            unsigned int cx0 = __shfl_xor(c0,32), dx0 = __shfl_xor(d0,32); \
            unsigned int ax1 = __shfl_xor(a1,32), bx1 = __shfl_xor(b1,32); \
            unsigned int cx1 = __shfl_xor(c1,32), dx1 = __shfl_xor(d1,32); \
            U8 u; \
            u.w[0] = hi ? cx0 : a0;  u.w[1] = hi ? dx0 : b0; \
            u.w[2] = hi ? c0 : ax0;  u.w[3] = hi ? d0 : bx0; \
            dA = u.v; \
            u.w[0] = hi ? cx1 : a1;  u.w[1] = hi ? dx1 : b1; \
            u.w[2] = hi ? c1 : ax1;  u.w[3] = hi ? d1 : bx1; \
            dB = u.v; \
        } while(0)
        MAKEPF(pf[0], pf[1], st0);
        MAKEPF(pf[2], pf[3], st1);
        #undef MAKEPF

        __builtin_amdgcn_s_setprio(1);
        #pragma unroll
        for (int dt = 0; dt < 4; ++dt){
            const int rowv = (dt<<5) + lq;
            #pragma unroll
            for (int f = 0; f < 4; ++f){
                const int col = (((f<<1) + hi) ^ (lq & 7)) << 3;
                bf16x8 vf = *reinterpret_cast<const bf16x8*>(&Vbuf[(rowv<<6) + col]);
                oacc[dt] = __builtin_amdgcn_mfma_f32_32x32x16_bf16(vf, pf[f], oacc[dt], 0, 0, 0);
            }
        }
        __builtin_amdgcn_s_setprio(0);

        __syncthreads();
        buf ^= 1;
    }
    #undef STAGE

    const float rl = 1.0f / l_run;
    unsigned short* oL = lO + wave*(32*132);
    #pragma unroll
    for (int dt = 0; dt < 4; ++dt)
        #pragma unroll
        for (int g = 0; g < 4; ++g){
            u16x4 w = { f2b(oacc[dt][g*4+0]*rl), f2b(oacc[dt][g*4+1]*rl),
                        f2b(oacc[dt][g*4+2]*rl), f2b(oacc[dt][g*4+3]*rl) };
            *reinterpret_cast<u16x4*>(&oL[lq*132 + (dt<<5) + (hi<<2) + (g<<3)]) = w;
        }
    #pragma unroll
    for (int i = 0; i < 16; ++i){
        const int q = (i<<1) + hi;
        u16x4 w = *reinterpret_cast<const u16x4*>(&oL[q*132 + (lq<<2)]);
        *reinterpret_cast<u16x4*>(&aout[(size_t)(b*SEQ + q0w + q)*DIMS + h*HD + (lq<<2)]) = w;
    }
}

// ---------------- launcher ----------------

extern "C" void kernel_launch(void* const* d_in, const int* in_sizes, int n_in,
                              void* d_out, int out_size, void* d_ws, size_t ws_size,
                              hipStream_t stream)
{
    const float* x    = (const float*)d_in[0];
    const float* rope = (const float*)d_in[1];
    const float* wq   = (const float*)d_in[2];
    const float* wk   = (const float*)d_in[3];
    const float* wv   = (const float*)d_in[4];
    const float* wo   = (const float*)d_in[5];
    const float* bo   = (const float*)d_in[6];
    float* out = (float*)d_out;

    char* ws = (char*)d_ws;
    unsigned short* x_bf   = (unsigned short*)(ws + 0);            // 16.8 MB
    unsigned short* wqkv   = (unsigned short*)(ws + 16777216);     // 25.2 MB
    unsigned short* wo_bf  = (unsigned short*)(ws + 41943040);     // 8.4 MB
    float*          cos_t  = (float*)(ws + 50331648);              // 1 MB
    float*          sin_t  = (float*)(ws + 51380224);              // 1 MB
    unsigned short* qkv    = (unsigned short*)(ws + 52428800);     // 50.3 MB
    unsigned short* vt     = (unsigned short*)(ws + 16777216);     // alias wqkv
    unsigned short* a_out  = (unsigned short*)(ws + 0);            // alias x_bf

    k_f32bf16<<<8192, 256, 0, stream>>>(x,  x_bf,              2097152);
    k_f32bf16<<<4096, 256, 0, stream>>>(wq, wqkv,              1048576);
    k_f32bf16<<<4096, 256, 0, stream>>>(wk, wqkv + 4194304,    1048576);
    k_f32bf16<<<4096, 256, 0, stream>>>(wv, wqkv + 8388608,    1048576);
    k_f32bf16<<<4096, 256, 0, stream>>>(wo, wo_bf,             1048576);
    k_cossin <<<1024, 256, 0, stream>>>(rope, cos_t, sin_t, SEQ*HD);

    // QKV projection: m97 128^2 kernel, grid 32*48 = 1536
    k_gemm_bt<0><<<(MROWS/128)*(QKVN/128), 256, 0, stream>>>(x_bf, wqkv, qkv, nullptr, MROWS, QKVN, DIMS);

    // RoPE in place on Q,K (vectorized bf16x8)
    k_rope<<<2048, 256, 0, stream>>>(qkv, cos_t, sin_t);

    k_vtrans<<<dim3(SEQ/64, HD/64, BATCH*HEADS), 256, 0, stream>>>(qkv, vt);

    k_attn<<<dim3(SEQ/256, BATCH*HEADS), 512, 0, stream>>>(qkv, vt, a_out);

    // output projection + bias
    k_gemm_bt<1><<<(MROWS/128)*(DIMS/128), 256, 0, stream>>>(a_out, wo_bf, out, bo, MROWS, DIMS, DIMS);
}

// Round 7
// 287.461 us; speedup vs baseline: 1.0911x; 1.0636x over previous
//
#include <hip/hip_runtime.h>
#include <hip/hip_bf16.h>
#include <stdint.h>

// Problem constants
#define DIMS  2048
#define HEADS 16
#define HD    128
#define BATCH 2
#define SEQ   2048
#define MROWS (BATCH*SEQ)   // 4096
#define QKVN  (3*DIMS)      // 6144

using bf16x8 = __attribute__((ext_vector_type(8))) short;
using f32x4  = __attribute__((ext_vector_type(4))) float;
using f32x16 = __attribute__((ext_vector_type(16))) float;
using u16x4  = __attribute__((ext_vector_type(4))) unsigned short;

__device__ __forceinline__ unsigned short f2b(float f){
    __hip_bfloat16 h = __float2bfloat16(f);
    return *reinterpret_cast<unsigned short*>(&h);
}
__device__ __forceinline__ float b2f(unsigned short u){
    __hip_bfloat16 h;
    *reinterpret_cast<unsigned short*>(&h) = u;
    return __bfloat162float(h);
}
__device__ __forceinline__ unsigned int pkbf(float lo, float hi){
    return (unsigned int)f2b(lo) | ((unsigned int)f2b(hi) << 16);
}

// async global->LDS, 16B per lane. LDS dest is wave-uniform base (+lane*16 implicit).
__device__ __forceinline__ void glds16(const void* g, void* l){
    __builtin_amdgcn_global_load_lds(
        (const __attribute__((address_space(1))) unsigned int*)g,
        (__attribute__((address_space(3))) unsigned int*)l, 16, 0, 0);
}

// ---------------- elementwise prep kernels ----------------

__global__ void k_f32bf16(const float* __restrict__ src, unsigned short* __restrict__ dst, int n4){
    int i = blockIdx.x*blockDim.x + threadIdx.x;
    if (i >= n4) return;
    const float4 v = reinterpret_cast<const float4*>(src)[i];
    u16x4 o = { f2b(v.x), f2b(v.y), f2b(v.z), f2b(v.w) };
    *reinterpret_cast<u16x4*>(dst + 4*(size_t)i) = o;
}

// 4 weight matrices (each 2048x2048 f32) -> bf16, one launch
__global__ void k_wconv4(const float* __restrict__ w0, const float* __restrict__ w1,
                         const float* __restrict__ w2, const float* __restrict__ w3,
                         unsigned short* __restrict__ d0, unsigned short* __restrict__ d1,
                         unsigned short* __restrict__ d2, unsigned short* __restrict__ d3){
    const int sel = blockIdx.y;
    const float* src = sel==0 ? w0 : sel==1 ? w1 : sel==2 ? w2 : w3;
    unsigned short* dst = sel==0 ? d0 : sel==1 ? d1 : sel==2 ? d2 : d3;
    const int i = blockIdx.x*blockDim.x + threadIdx.x;   // 4096*256 = 1048576 = exact
    const float4 v = reinterpret_cast<const float4*>(src)[i];
    u16x4 o = { f2b(v.x), f2b(v.y), f2b(v.z), f2b(v.w) };
    *reinterpret_cast<u16x4*>(dst + 4*(size_t)i) = o;
}

__global__ void k_cossin(const float* __restrict__ r, float* __restrict__ c, float* __restrict__ s, int n){
    int i = blockIdx.x*blockDim.x + threadIdx.x;
    if (i >= n) return;
    float v = r[i];
    c[i] = cosf(v);
    s[i] = sinf(v);
}

// RoPE in-place on Q and K sections of qkv [MROWS][6144] bf16 — vectorized bf16x8.
__global__ void k_rope(unsigned short* __restrict__ qkv,
                       const float* __restrict__ ct, const float* __restrict__ st){
    const int idx = blockIdx.x*blockDim.x + threadIdx.x;   // B*SEQ*HEADS*8 = 524288
    const int d0 = (idx & 7) << 3;
    const int h  = (idx >> 3) & (HEADS-1);
    const int l  = (idx >> 7) & (SEQ-1);
    const int b  = idx >> 18;

    const float4* cp = reinterpret_cast<const float4*>(ct + l*HD + d0);
    const float4* sp = reinterpret_cast<const float4*>(st + l*HD + d0);
    const float4 cl0 = cp[0],  cl1 = cp[1];
    const float4 sl0 = sp[0],  sl1 = sp[1];
    const float4 cu0 = cp[16], cu1 = cp[17];   // +64 floats
    const float4 su0 = sp[16], su1 = sp[17];
    const float cl[8] = {cl0.x,cl0.y,cl0.z,cl0.w, cl1.x,cl1.y,cl1.z,cl1.w};
    const float sl[8] = {sl0.x,sl0.y,sl0.z,sl0.w, sl1.x,sl1.y,sl1.z,sl1.w};
    const float cu[8] = {cu0.x,cu0.y,cu0.z,cu0.w, cu1.x,cu1.y,cu1.z,cu1.w};
    const float su[8] = {su0.x,su0.y,su0.z,su0.w, su1.x,su1.y,su1.z,su1.w};

    unsigned short* base = qkv + (size_t)(b*SEQ + l)*QKVN + h*HD + d0;
    #pragma unroll
    for (int s = 0; s < 2; ++s){               // s=0: Q, s=1: K
        unsigned short* rp = base + s*DIMS;
        bf16x8 lo = *reinterpret_cast<const bf16x8*>(rp);
        bf16x8 hi = *reinterpret_cast<const bf16x8*>(rp + 64);
        bf16x8 olo, ohi;
        #pragma unroll
        for (int j = 0; j < 8; ++j){
            const float x1 = b2f((unsigned short)lo[j]);
            const float x2 = b2f((unsigned short)hi[j]);
            olo[j] = (short)f2b(x1*cl[j] - x2*sl[j]);
            ohi[j] = (short)f2b(x2*cu[j] + x1*su[j]);
        }
        *reinterpret_cast<bf16x8*>(rp)      = olo;
        *reinterpret_cast<bf16x8*>(rp + 64) = ohi;
    }
}

// V transpose: qkv V section [b][l][h*128+d] -> vt[(b*16+h)*128 + d][l]
__global__ void k_vtrans(const unsigned short* __restrict__ qkv, unsigned short* __restrict__ vt){
    __shared__ unsigned short t[64*68];
    const int lt = blockIdx.x;
    const int dt = blockIdx.y;
    const int bh = blockIdx.z;
    const int b = bh >> 4, h = bh & 15;
    const int tid = threadIdx.x;
    const int l0 = lt << 6;
    #pragma unroll
    for (int it = 0; it < 4; ++it){
        const int c = tid + (it<<8);
        const int l = c >> 4;
        const int d4 = (c & 15) << 2;
        const u16x4 v = *reinterpret_cast<const u16x4*>(
            qkv + (size_t)(b*SEQ + l0 + l)*QKVN + 2*DIMS + h*HD + (dt<<6) + d4);
        *reinterpret_cast<u16x4*>(&t[l*68 + d4]) = v;
    }
    __syncthreads();
    #pragma unroll
    for (int it = 0; it < 4; ++it){
        const int c = tid + (it<<8);
        const int d = c >> 4;
        const int l4 = (c & 15) << 2;
        u16x4 o = { t[(l4+0)*68 + d], t[(l4+1)*68 + d], t[(l4+2)*68 + d], t[(l4+3)*68 + d] };
        *reinterpret_cast<u16x4*>(&vt[((size_t)bh*HD + (dt<<6) + d)*SEQ + l0 + l4]) = o;
    }
}

// ---------------- 128x128 GEMM (m97 structure) — both projections ----------------

template<int FINAL>
__global__ __launch_bounds__(256) void k_gemm_bt(
    const unsigned short* __restrict__ A, const unsigned short* __restrict__ B,
    void* __restrict__ C, const float* __restrict__ bias, int M, int N, int K)
{
    __shared__ unsigned short lA[128*64];
    __shared__ unsigned short lB[128*64];
    const int tid  = threadIdx.x;
    const int lane = tid & 63;
    const int wave = tid >> 6;

    const int nbx = N >> 7;
    const int nwg = gridDim.x;
    const int cpx = nwg >> 3;
    const int bid = blockIdx.x;
    const int wg  = (bid & 7)*cpx + (bid >> 3);
    const int m0 = (wg / nbx) << 7;
    const int n0 = (wg % nbx) << 7;

    const int wr = (wave >> 1) << 6;
    const int wc = (wave & 1) << 6;

    f32x4 acc[4][4] = {};

    const int srow_base = (wave<<3) + (lane>>3);
    const int schunk = lane & 7;

    for (int k0 = 0; k0 < K; k0 += 64){
        #pragma unroll
        for (int i = 0; i < 4; ++i){
            const int row  = (i<<5) + srow_base;
            const int scol = k0 + ((schunk ^ (row & 7)) << 3);
            glds16(A + (size_t)(m0 + row)*K + scol, &lA[((i<<5) + (wave<<3)) << 6]);
            glds16(B + (size_t)(n0 + row)*K + scol, &lB[((i<<5) + (wave<<3)) << 6]);
        }
        __syncthreads();
        #pragma unroll
        for (int ks = 0; ks < 2; ++ks){
            bf16x8 af[4], bfr[4];
            const int colbase = (ks<<5) + ((lane>>4)<<3);
            #pragma unroll
            for (int mi = 0; mi < 4; ++mi){
                const int row = wr + (mi<<4) + (lane & 15);
                af[mi] = *reinterpret_cast<const bf16x8*>(&lA[(row<<6) + (colbase ^ ((row&7)<<3))]);
            }
            #pragma unroll
            for (int ni = 0; ni < 4; ++ni){
                const int row = wc + (ni<<4) + (lane & 15);
                bfr[ni] = *reinterpret_cast<const bf16x8*>(&lB[(row<<6) + (colbase ^ ((row&7)<<3))]);
            }
            #pragma unroll
            for (int mi = 0; mi < 4; ++mi)
                #pragma unroll
                for (int ni = 0; ni < 4; ++ni)
                    acc[mi][ni] = __builtin_amdgcn_mfma_f32_16x16x32_bf16(af[mi], bfr[ni], acc[mi][ni], 0, 0, 0);
        }
        __syncthreads();
    }

    const int r0 = (lane >> 4) << 2;
    const int cn = lane & 15;
    #pragma unroll
    for (int mi = 0; mi < 4; ++mi)
        #pragma unroll
        for (int r = 0; r < 4; ++r){
            const int gm = m0 + wr + (mi<<4) + r0 + r;
            #pragma unroll
            for (int ni = 0; ni < 4; ++ni){
                const int gn = n0 + wc + (ni<<4) + cn;
                const float v = acc[mi][ni][r];
                if (FINAL)
                    reinterpret_cast<float*>(C)[(size_t)gm*N + gn] = v + bias[gn];
                else
                    reinterpret_cast<unsigned short*>(C)[(size_t)gm*N + gn] = f2b(v);
            }
        }
}

// ---------------- flash attention, swapped-operand 32x32, 4-wave blocks ----------------
// grid (SEQ/128=16, bh=32), block 256 (4 waves x 32 q-rows). KV tile 64, dbuf.
// LDS union 64KB: loop uses lK[2][64*128] (elems 0..16384) + lV[2][128*64]
// (elems 16384..32768); epilogue reuses elems 0..16896 as lO[4][32][132].
// 2 blocks/CU (128KB), 512 blocks = 1 full round of 256 CUs.

union U8 { unsigned int w[4]; bf16x8 v; };

__global__ __launch_bounds__(256, 2) void k_attn(
    const unsigned short* __restrict__ qkv, const unsigned short* __restrict__ vt,
    unsigned short* __restrict__ aout)
{
    __shared__ unsigned short smem[32768];   // 64 KB

    const int tid  = threadIdx.x;
    const int lane = tid & 63;
    const int wave = tid >> 6;               // 0..3
    const int lq   = lane & 31;
    const int hi   = lane >> 5;
    const int bh = blockIdx.y;
    const int b = bh >> 4, h = bh & 15;
    const int q0w = (blockIdx.x << 7) + (wave << 5);

    const unsigned short* Kb = qkv + (size_t)b*SEQ*QKVN + DIMS + h*HD;
    const unsigned short* Vb = vt + (size_t)bh*HD*SEQ;

    // Q fragments (B-operand: col=q=lane&31, k=hi*8+j), pre-scaled by log2e/sqrt(HD)
    bf16x8 qf[8];
    {
        const float qscale = 0.08838834764831845f * 1.4426950408889634f;
        const unsigned short* qp = qkv + (size_t)(b*SEQ + q0w + lq)*QKVN + h*HD + (hi<<3);
        #pragma unroll
        for (int ks = 0; ks < 8; ++ks){
            bf16x8 tv = *reinterpret_cast<const bf16x8*>(qp + (ks<<4));
            #pragma unroll
            for (int j = 0; j < 8; ++j)
                tv[j] = (short)f2b(b2f((unsigned short)tv[j]) * qscale);
            qf[ks] = tv;
        }
    }

    float m_run = -3e38f, l_run = 0.f;
    f32x16 oacc[4] = {};

    // 4-wave staging: per wave 4 K-glds (4 rows each) + 4 V-glds (8 rows each)
    #define STAGE(pb, kv0) do { \
        _Pragma("unroll") \
        for (int i = 0; i < 4; ++i){ \
            const int kr = (wave<<4) + (i<<2) + (lane>>4); \
            glds16(Kb + (size_t)((kv0) + kr)*QKVN + (((lane&15) ^ (kr&7))<<3), \
                   &smem[((pb)<<13) + (((wave<<4) + (i<<2))<<7)]); \
            const int dr = (wave<<5) + (i<<3) + (lane>>3); \
            glds16(Vb + (size_t)dr*SEQ + (kv0) + (((lane&7) ^ (dr&7))<<3), \
                   &smem[16384 + ((pb)<<13) + (((wave<<5) + (i<<3))<<6)]); \
        } \
    } while(0)

    int buf = 0;
    STAGE(0, 0);
    __syncthreads();

    for (int t = 0; t < SEQ/64; ++t){
        if (t < SEQ/64 - 1) STAGE(buf^1, (t+1)*64);

        const unsigned short* Kbuf = &smem[buf<<13];
        const unsigned short* Vbuf = &smem[16384 + (buf<<13)];

        // ---- S = K * Q  (S[kv][q]) ----
        f32x16 st0 = {}, st1 = {};
        __builtin_amdgcn_s_setprio(1);
        #pragma unroll
        for (int ks = 0; ks < 8; ++ks){
            const int col = (((ks<<1) + hi) ^ (lq & 7)) << 3;
            bf16x8 k0 = *reinterpret_cast<const bf16x8*>(&Kbuf[(lq<<7) + col]);
            bf16x8 k1 = *reinterpret_cast<const bf16x8*>(&Kbuf[((32+lq)<<7) + col]);
            st0 = __builtin_amdgcn_mfma_f32_32x32x16_bf16(k0, qf[ks], st0, 0, 0, 0);
            st1 = __builtin_amdgcn_mfma_f32_32x32x16_bf16(k1, qf[ks], st1, 0, 0, 0);
        }
        __builtin_amdgcn_s_setprio(0);

        // ---- online softmax (exp2 domain), per-lane column q ----
        float tmax = st0[0];
        #pragma unroll
        for (int r = 1; r < 16; ++r) tmax = fmaxf(tmax, st0[r]);
        #pragma unroll
        for (int r = 0; r < 16; ++r) tmax = fmaxf(tmax, st1[r]);
        tmax = fmaxf(tmax, __shfl_xor(tmax, 32));

        // defer-max (T13): skip rescale when max growth small (P bounded by 2^8)
        const bool defer = __all(tmax <= m_run + 8.0f);
        if (!defer){
            const float mnew = fmaxf(m_run, tmax);
            const float al = __builtin_amdgcn_exp2f(m_run - mnew);
            m_run = mnew;
            l_run *= al;
            #pragma unroll
            for (int dt = 0; dt < 4; ++dt) oacc[dt] *= al;
        }
        float tsum = 0.f;
        #pragma unroll
        for (int r = 0; r < 16; ++r){ float p = __builtin_amdgcn_exp2f(st0[r] - m_run); st0[r] = p; tsum += p; }
        #pragma unroll
        for (int r = 0; r < 16; ++r){ float p = __builtin_amdgcn_exp2f(st1[r] - m_run); st1[r] = p; tsum += p; }
        tsum += __shfl_xor(tsum, 32);
        l_run += tsum;

        // ---- P -> B-fragments via pack + permlane32_swap (T12) ----
        bf16x8 pf[4];
        #define MAKEPF(dA, dB, SV) do { \
            unsigned int a0 = pkbf(SV[0],SV[1]),  b0 = pkbf(SV[2],SV[3]); \
            unsigned int c0 = pkbf(SV[4],SV[5]),  d0 = pkbf(SV[6],SV[7]); \
            unsigned int a1 = pkbf(SV[8],SV[9]),  b1 = pkbf(SV[10],SV[11]); \
            unsigned int c1 = pkbf(SV[12],SV[13]),d1 = pkbf(SV[14],SV[15]); \
            asm("v_permlane32_swap_b32 %0, %1" : "+v"(a0), "+v"(c0)); \
            asm("v_permlane32_swap_b32 %0, %1" : "+v"(b0), "+v"(d0)); \
            asm("v_permlane32_swap_b32 %0, %1" : "+v"(a1), "+v"(c1)); \
            asm("v_permlane32_swap_b32 %0, %1" : "+v"(b1), "+v"(d1)); \
            U8 u; \
            u.w[0] = a0; u.w[1] = b0; u.w[2] = c0; u.w[3] = d0; dA = u.v; \
            u.w[0] = a1; u.w[1] = b1; u.w[2] = c1; u.w[3] = d1; dB = u.v; \
        } while(0)
        MAKEPF(pf[0], pf[1], st0);
        MAKEPF(pf[2], pf[3], st1);
        #undef MAKEPF

        // ---- O^T += V^T * P ----
        __builtin_amdgcn_s_setprio(1);
        #pragma unroll
        for (int dt = 0; dt < 4; ++dt){
            const int rowv = (dt<<5) + lq;
            #pragma unroll
            for (int f = 0; f < 4; ++f){
                const int col = (((f<<1) + hi) ^ (lq & 7)) << 3;
                bf16x8 vf = *reinterpret_cast<const bf16x8*>(&Vbuf[(rowv<<6) + col]);
                oacc[dt] = __builtin_amdgcn_mfma_f32_32x32x16_bf16(vf, pf[f], oacc[dt], 0, 0, 0);
            }
        }
        __builtin_amdgcn_s_setprio(0);

        __syncthreads();
        buf ^= 1;
    }
    #undef STAGE

    // ---- epilogue: O^T -> per-wave LDS transpose (reusing smem) -> coalesced global ----
    const float rl = 1.0f / l_run;
    unsigned short* oL = smem + wave*(32*132);
    #pragma unroll
    for (int dt = 0; dt < 4; ++dt)
        #pragma unroll
        for (int g = 0; g < 4; ++g){
            u16x4 w = { f2b(oacc[dt][g*4+0]*rl), f2b(oacc[dt][g*4+1]*rl),
                        f2b(oacc[dt][g*4+2]*rl), f2b(oacc[dt][g*4+3]*rl) };
            *reinterpret_cast<u16x4*>(&oL[lq*132 + (dt<<5) + (hi<<2) + (g<<3)]) = w;
        }
    #pragma unroll
    for (int i = 0; i < 16; ++i){
        const int q = (i<<1) + hi;
        u16x4 w = *reinterpret_cast<const u16x4*>(&oL[q*132 + (lq<<2)]);
        *reinterpret_cast<u16x4*>(&aout[(size_t)(b*SEQ + q0w + q)*DIMS + h*HD + (lq<<2)]) = w;
    }
}

// ---------------- launcher ----------------

extern "C" void kernel_launch(void* const* d_in, const int* in_sizes, int n_in,
                              void* d_out, int out_size, void* d_ws, size_t ws_size,
                              hipStream_t stream)
{
    const float* x    = (const float*)d_in[0];
    const float* rope = (const float*)d_in[1];
    const float* wq   = (const float*)d_in[2];
    const float* wk   = (const float*)d_in[3];
    const float* wv   = (const float*)d_in[4];
    const float* wo   = (const float*)d_in[5];
    const float* bo   = (const float*)d_in[6];
    float* out = (float*)d_out;

    char* ws = (char*)d_ws;
    unsigned short* x_bf   = (unsigned short*)(ws + 0);            // 16.8 MB
    unsigned short* wqkv   = (unsigned short*)(ws + 16777216);     // 25.2 MB
    unsigned short* wo_bf  = (unsigned short*)(ws + 41943040);     // 8.4 MB
    float*          cos_t  = (float*)(ws + 50331648);              // 1 MB
    float*          sin_t  = (float*)(ws + 51380224);              // 1 MB
    unsigned short* qkv    = (unsigned short*)(ws + 52428800);     // 50.3 MB
    unsigned short* vt     = (unsigned short*)(ws + 16777216);     // alias wqkv
    unsigned short* a_out  = (unsigned short*)(ws + 0);            // alias x_bf

    k_f32bf16<<<8192, 256, 0, stream>>>(x, x_bf, 2097152);
    k_wconv4<<<dim3(4096,4), 256, 0, stream>>>(wq, wk, wv, wo,
                                               wqkv, wqkv + 4194304, wqkv + 8388608, wo_bf);
    k_cossin <<<1024, 256, 0, stream>>>(rope, cos_t, sin_t, SEQ*HD);

    // QKV projection: m97 128^2 kernel, grid 32*48 = 1536
    k_gemm_bt<0><<<(MROWS/128)*(QKVN/128), 256, 0, stream>>>(x_bf, wqkv, qkv, nullptr, MROWS, QKVN, DIMS);

    // RoPE in place on Q,K (vectorized bf16x8)
    k_rope<<<2048, 256, 0, stream>>>(qkv, cos_t, sin_t);

    k_vtrans<<<dim3(SEQ/64, HD/64, BATCH*HEADS), 256, 0, stream>>>(qkv, vt);

    // attention: 4-wave blocks, grid 16x32 = 512 = 2 blocks/CU x 256 CUs
    k_attn<<<dim3(SEQ/128, BATCH*HEADS), 256, 0, stream>>>(qkv, vt, a_out);

    // output projection + bias
    k_gemm_bt<1><<<(MROWS/128)*(DIMS/128), 256, 0, stream>>>(a_out, wo_bf, out, bo, MROWS, DIMS, DIMS);
}

// Round 8
// 285.904 us; speedup vs baseline: 1.0970x; 1.0054x over previous
//
#include <hip/hip_runtime.h>
#include <hip/hip_bf16.h>
#include <stdint.h>

// Problem constants
#define DIMS  2048
#define HEADS 16
#define HD    128
#define BATCH 2
#define SEQ   2048
#define MROWS (BATCH*SEQ)   // 4096
#define QKVN  (3*DIMS)      // 6144

using bf16x8 = __attribute__((ext_vector_type(8))) short;
using f32x4  = __attribute__((ext_vector_type(4))) float;
using f32x16 = __attribute__((ext_vector_type(16))) float;
using u16x4  = __attribute__((ext_vector_type(4))) unsigned short;

__device__ __forceinline__ unsigned short f2b(float f){
    __hip_bfloat16 h = __float2bfloat16(f);
    return *reinterpret_cast<unsigned short*>(&h);
}
__device__ __forceinline__ float b2f(unsigned short u){
    __hip_bfloat16 h;
    *reinterpret_cast<unsigned short*>(&h) = u;
    return __bfloat162float(h);
}
__device__ __forceinline__ unsigned int pkbf(float lo, float hi){
    return (unsigned int)f2b(lo) | ((unsigned int)f2b(hi) << 16);
}

// async global->LDS, 16B per lane. LDS dest is wave-uniform base (+lane*16 implicit).
__device__ __forceinline__ void glds16(const void* g, void* l){
    __builtin_amdgcn_global_load_lds(
        (const __attribute__((address_space(1))) unsigned int*)g,
        (__attribute__((address_space(3))) unsigned int*)l, 16, 0, 0);
}

// ---------------- fused prep: x->bf16, 4x w->bf16, cos/sin table ----------------
// grid (4096, 7): y 0..3 -> weight y; y 4..5 -> x halves; y 6 -> cossin (1024 blocks active)

__global__ void k_prep(const float* __restrict__ x,
                       const float* __restrict__ w0, const float* __restrict__ w1,
                       const float* __restrict__ w2, const float* __restrict__ w3,
                       const float* __restrict__ rope,
                       unsigned short* __restrict__ x_bf,
                       unsigned short* __restrict__ d0, unsigned short* __restrict__ d1,
                       unsigned short* __restrict__ d2, unsigned short* __restrict__ d3,
                       float* __restrict__ ct, float* __restrict__ st){
    const int y = blockIdx.y;
    if (y == 6){
        const int i = blockIdx.x*blockDim.x + threadIdx.x;
        if (i >= SEQ*HD) return;
        const float v = rope[i];
        ct[i] = cosf(v);
        st[i] = sinf(v);
        return;
    }
    const float* src;
    unsigned short* dst;
    size_t off = 0;
    if      (y == 0){ src = w0; dst = d0; }
    else if (y == 1){ src = w1; dst = d1; }
    else if (y == 2){ src = w2; dst = d2; }
    else if (y == 3){ src = w3; dst = d3; }
    else            { src = x;  dst = x_bf; off = (size_t)(y - 4) * 1048576; }
    const size_t i = off + blockIdx.x*blockDim.x + threadIdx.x;
    const float4 v = reinterpret_cast<const float4*>(src)[i];
    u16x4 o = { f2b(v.x), f2b(v.y), f2b(v.z), f2b(v.w) };
    *reinterpret_cast<u16x4*>(dst + 4*i) = o;
}

// ---------------- fused K-rope + V-transpose ----------------
// grid 4096 x 256. bid < 2048: RoPE in-place on K section (bf16x8 vectorized).
// bid >= 2048: V transpose qkv[b][l][2*DIMS + h*128+d] -> vt[(b*16+h)*128+d][l].

__global__ void k_kropevt(unsigned short* __restrict__ qkv,
                          const float* __restrict__ ct, const float* __restrict__ st,
                          unsigned short* __restrict__ vt){
    __shared__ unsigned short t[64*68];
    const int bid = blockIdx.x;
    if (bid < 2048){
        const int idx = bid*blockDim.x + threadIdx.x;   // 524288
        const int d0 = (idx & 7) << 3;
        const int h  = (idx >> 3) & (HEADS-1);
        const int l  = (idx >> 7) & (SEQ-1);
        const int b  = idx >> 18;
        const float4* cp = reinterpret_cast<const float4*>(ct + l*HD + d0);
        const float4* sp = reinterpret_cast<const float4*>(st + l*HD + d0);
        const float4 cl0 = cp[0],  cl1 = cp[1];
        const float4 sl0 = sp[0],  sl1 = sp[1];
        const float4 cu0 = cp[16], cu1 = cp[17];
        const float4 su0 = sp[16], su1 = sp[17];
        const float cl[8] = {cl0.x,cl0.y,cl0.z,cl0.w, cl1.x,cl1.y,cl1.z,cl1.w};
        const float sl[8] = {sl0.x,sl0.y,sl0.z,sl0.w, sl1.x,sl1.y,sl1.z,sl1.w};
        const float cu[8] = {cu0.x,cu0.y,cu0.z,cu0.w, cu1.x,cu1.y,cu1.z,cu1.w};
        const float su[8] = {su0.x,su0.y,su0.z,su0.w, su1.x,su1.y,su1.z,su1.w};
        unsigned short* rp = qkv + (size_t)(b*SEQ + l)*QKVN + DIMS + h*HD + d0;  // K section
        bf16x8 lo = *reinterpret_cast<const bf16x8*>(rp);
        bf16x8 hi = *reinterpret_cast<const bf16x8*>(rp + 64);
        bf16x8 olo, ohi;
        #pragma unroll
        for (int j = 0; j < 8; ++j){
            const float x1 = b2f((unsigned short)lo[j]);
            const float x2 = b2f((unsigned short)hi[j]);
            olo[j] = (short)f2b(x1*cl[j] - x2*sl[j]);
            ohi[j] = (short)f2b(x2*cu[j] + x1*su[j]);
        }
        *reinterpret_cast<bf16x8*>(rp)      = olo;
        *reinterpret_cast<bf16x8*>(rp + 64) = ohi;
        return;
    }
    // ---- V transpose ----
    const int bid2 = bid - 2048;
    const int lt = bid2 & 31;
    const int dt = (bid2 >> 5) & 1;
    const int bh = bid2 >> 6;
    const int b = bh >> 4, h = bh & 15;
    const int tid = threadIdx.x;
    const int l0 = lt << 6;
    #pragma unroll
    for (int it = 0; it < 4; ++it){
        const int c = tid + (it<<8);
        const int l = c >> 4;
        const int d4 = (c & 15) << 2;
        const u16x4 v = *reinterpret_cast<const u16x4*>(
            qkv + (size_t)(b*SEQ + l0 + l)*QKVN + 2*DIMS + h*HD + (dt<<6) + d4);
        *reinterpret_cast<u16x4*>(&t[l*68 + d4]) = v;
    }
    __syncthreads();
    #pragma unroll
    for (int it = 0; it < 4; ++it){
        const int c = tid + (it<<8);
        const int d = c >> 4;
        const int l4 = (c & 15) << 2;
        u16x4 o = { t[(l4+0)*68 + d], t[(l4+1)*68 + d], t[(l4+2)*68 + d], t[(l4+3)*68 + d] };
        *reinterpret_cast<u16x4*>(&vt[((size_t)bh*HD + (dt<<6) + d)*SEQ + l0 + l4]) = o;
    }
}

// ---------------- 128x128 GEMM (m97 structure) — both projections ----------------

template<int FINAL>
__global__ __launch_bounds__(256) void k_gemm_bt(
    const unsigned short* __restrict__ A, const unsigned short* __restrict__ B,
    void* __restrict__ C, const float* __restrict__ bias, int M, int N, int K)
{
    __shared__ unsigned short lA[128*64];
    __shared__ unsigned short lB[128*64];
    const int tid  = threadIdx.x;
    const int lane = tid & 63;
    const int wave = tid >> 6;

    const int nbx = N >> 7;
    const int nwg = gridDim.x;
    const int cpx = nwg >> 3;
    const int bid = blockIdx.x;
    const int wg  = (bid & 7)*cpx + (bid >> 3);
    const int m0 = (wg / nbx) << 7;
    const int n0 = (wg % nbx) << 7;

    const int wr = (wave >> 1) << 6;
    const int wc = (wave & 1) << 6;

    f32x4 acc[4][4] = {};

    const int srow_base = (wave<<3) + (lane>>3);
    const int schunk = lane & 7;

    for (int k0 = 0; k0 < K; k0 += 64){
        #pragma unroll
        for (int i = 0; i < 4; ++i){
            const int row  = (i<<5) + srow_base;
            const int scol = k0 + ((schunk ^ (row & 7)) << 3);
            glds16(A + (size_t)(m0 + row)*K + scol, &lA[((i<<5) + (wave<<3)) << 6]);
            glds16(B + (size_t)(n0 + row)*K + scol, &lB[((i<<5) + (wave<<3)) << 6]);
        }
        __syncthreads();
        #pragma unroll
        for (int ks = 0; ks < 2; ++ks){
            bf16x8 af[4], bfr[4];
            const int colbase = (ks<<5) + ((lane>>4)<<3);
            #pragma unroll
            for (int mi = 0; mi < 4; ++mi){
                const int row = wr + (mi<<4) + (lane & 15);
                af[mi] = *reinterpret_cast<const bf16x8*>(&lA[(row<<6) + (colbase ^ ((row&7)<<3))]);
            }
            #pragma unroll
            for (int ni = 0; ni < 4; ++ni){
                const int row = wc + (ni<<4) + (lane & 15);
                bfr[ni] = *reinterpret_cast<const bf16x8*>(&lB[(row<<6) + (colbase ^ ((row&7)<<3))]);
            }
            #pragma unroll
            for (int mi = 0; mi < 4; ++mi)
                #pragma unroll
                for (int ni = 0; ni < 4; ++ni)
                    acc[mi][ni] = __builtin_amdgcn_mfma_f32_16x16x32_bf16(af[mi], bfr[ni], acc[mi][ni], 0, 0, 0);
        }
        __syncthreads();
    }

    const int r0 = (lane >> 4) << 2;
    const int cn = lane & 15;
    #pragma unroll
    for (int mi = 0; mi < 4; ++mi)
        #pragma unroll
        for (int r = 0; r < 4; ++r){
            const int gm = m0 + wr + (mi<<4) + r0 + r;
            #pragma unroll
            for (int ni = 0; ni < 4; ++ni){
                const int gn = n0 + wc + (ni<<4) + cn;
                const float v = acc[mi][ni][r];
                if (FINAL)
                    reinterpret_cast<float*>(C)[(size_t)gm*N + gn] = v + bias[gn];
                else
                    reinterpret_cast<unsigned short*>(C)[(size_t)gm*N + gn] = f2b(v);
            }
        }
}

// ---------------- flash attention, swapped-operand 32x32, 4-wave blocks ----------------
// grid (SEQ/128=16, bh=32), block 256 (4 waves x 32 q-rows). KV tile 64, dbuf.
// Q-rope applied in-register at Q-load (pairs (d, d+64) = (qf[ks][j], qf[ks+4][j])).
// LDS union 64KB; 2 blocks/CU, 512 blocks = 1 full round.

union U8 { unsigned int w[4]; bf16x8 v; };

__global__ __launch_bounds__(256, 2) void k_attn(
    const unsigned short* __restrict__ qkv, const unsigned short* __restrict__ vt,
    const float* __restrict__ ct, const float* __restrict__ st,
    unsigned short* __restrict__ aout)
{
    __shared__ unsigned short smem[32768];   // 64 KB

    const int tid  = threadIdx.x;
    const int lane = tid & 63;
    const int wave = tid >> 6;               // 0..3
    const int lq   = lane & 31;
    const int hi   = lane >> 5;
    const int bh = blockIdx.y;
    const int b = bh >> 4, h = bh & 15;
    const int q0w = (blockIdx.x << 7) + (wave << 5);

    const unsigned short* Kb = qkv + (size_t)b*SEQ*QKVN + DIMS + h*HD;
    const unsigned short* Vb = vt + (size_t)bh*HD*SEQ;

    // Q fragments (B-operand: col=q=lane&31, k=hi*8+j) with in-register RoPE,
    // pre-scaled by log2e/sqrt(HD). d(ks,j) = ks*16 + hi*8 + j; pair = qf[ks+4][j].
    bf16x8 qf[8];
    {
        const float qscale = 0.08838834764831845f * 1.4426950408889634f;
        const int l = q0w + lq;
        const unsigned short* qp = qkv + (size_t)(b*SEQ + l)*QKVN + h*HD + (hi<<3);
        #pragma unroll
        for (int ks = 0; ks < 8; ++ks)
            qf[ks] = *reinterpret_cast<const bf16x8*>(qp + (ks<<4));
        #pragma unroll
        for (int ks = 0; ks < 4; ++ks){
            const int d0 = (ks<<4) + (hi<<3);
            const float4 c0 = *reinterpret_cast<const float4*>(ct + l*HD + d0);
            const float4 c1 = *reinterpret_cast<const float4*>(ct + l*HD + d0 + 4);
            const float4 s0 = *reinterpret_cast<const float4*>(st + l*HD + d0);
            const float4 s1 = *reinterpret_cast<const float4*>(st + l*HD + d0 + 4);
            const float4 C0 = *reinterpret_cast<const float4*>(ct + l*HD + d0 + 64);
            const float4 C1 = *reinterpret_cast<const float4*>(ct + l*HD + d0 + 68);
            const float4 S0 = *reinterpret_cast<const float4*>(st + l*HD + d0 + 64);
            const float4 S1 = *reinterpret_cast<const float4*>(st + l*HD + d0 + 68);
            const float cl[8] = {c0.x,c0.y,c0.z,c0.w, c1.x,c1.y,c1.z,c1.w};
            const float sl[8] = {s0.x,s0.y,s0.z,s0.w, s1.x,s1.y,s1.z,s1.w};
            const float cu[8] = {C0.x,C0.y,C0.z,C0.w, C1.x,C1.y,C1.z,C1.w};
            const float su[8] = {S0.x,S0.y,S0.z,S0.w, S1.x,S1.y,S1.z,S1.w};
            #pragma unroll
            for (int j = 0; j < 8; ++j){
                const float x1 = b2f((unsigned short)qf[ks][j]);
                const float x2 = b2f((unsigned short)qf[ks+4][j]);
                qf[ks][j]   = (short)f2b((x1*cl[j] - x2*sl[j]) * qscale);
                qf[ks+4][j] = (short)f2b((x2*cu[j] + x1*su[j]) * qscale);
            }
        }
    }

    float m_run = -3e38f, l_run = 0.f;
    f32x16 oacc[4] = {};

    #define STAGE(pb, kv0) do { \
        _Pragma("unroll") \
        for (int i = 0; i < 4; ++i){ \
            const int kr = (wave<<4) + (i<<2) + (lane>>4); \
            glds16(Kb + (size_t)((kv0) + kr)*QKVN + (((lane&15) ^ (kr&7))<<3), \
                   &smem[((pb)<<13) + (((wave<<4) + (i<<2))<<7)]); \
            const int dr = (wave<<5) + (i<<3) + (lane>>3); \
            glds16(Vb + (size_t)dr*SEQ + (kv0) + (((lane&7) ^ (dr&7))<<3), \
                   &smem[16384 + ((pb)<<13) + (((wave<<5) + (i<<3))<<6)]); \
        } \
    } while(0)

    int buf = 0;
    STAGE(0, 0);
    __syncthreads();

    for (int t = 0; t < SEQ/64; ++t){
        if (t < SEQ/64 - 1) STAGE(buf^1, (t+1)*64);

        const unsigned short* Kbuf = &smem[buf<<13];
        const unsigned short* Vbuf = &smem[16384 + (buf<<13)];

        // ---- S = K * Q  (S[kv][q]) ----
        f32x16 st0 = {}, st1 = {};
        __builtin_amdgcn_s_setprio(1);
        #pragma unroll
        for (int ks = 0; ks < 8; ++ks){
            const int col = (((ks<<1) + hi) ^ (lq & 7)) << 3;
            bf16x8 k0 = *reinterpret_cast<const bf16x8*>(&Kbuf[(lq<<7) + col]);
            bf16x8 k1 = *reinterpret_cast<const bf16x8*>(&Kbuf[((32+lq)<<7) + col]);
            st0 = __builtin_amdgcn_mfma_f32_32x32x16_bf16(k0, qf[ks], st0, 0, 0, 0);
            st1 = __builtin_amdgcn_mfma_f32_32x32x16_bf16(k1, qf[ks], st1, 0, 0, 0);
        }
        __builtin_amdgcn_s_setprio(0);

        // ---- online softmax (exp2 domain), per-lane column q ----
        float tmax = st0[0];
        #pragma unroll
        for (int r = 1; r < 16; ++r) tmax = fmaxf(tmax, st0[r]);
        #pragma unroll
        for (int r = 0; r < 16; ++r) tmax = fmaxf(tmax, st1[r]);
        tmax = fmaxf(tmax, __shfl_xor(tmax, 32));

        // defer-max (T13): skip rescale when max growth small (P bounded by 2^8)
        const bool defer = __all(tmax <= m_run + 8.0f);
        if (!defer){
            const float mnew = fmaxf(m_run, tmax);
            const float al = __builtin_amdgcn_exp2f(m_run - mnew);
            m_run = mnew;
            l_run *= al;
            #pragma unroll
            for (int dt = 0; dt < 4; ++dt) oacc[dt] *= al;
        }
        float tsum = 0.f;
        #pragma unroll
        for (int r = 0; r < 16; ++r){ float p = __builtin_amdgcn_exp2f(st0[r] - m_run); st0[r] = p; tsum += p; }
        #pragma unroll
        for (int r = 0; r < 16; ++r){ float p = __builtin_amdgcn_exp2f(st1[r] - m_run); st1[r] = p; tsum += p; }
        tsum += __shfl_xor(tsum, 32);
        l_run += tsum;

        // ---- P -> B-fragments via pack + permlane32_swap (T12) ----
        bf16x8 pf[4];
        #define MAKEPF(dA, dB, SV) do { \
            unsigned int a0 = pkbf(SV[0],SV[1]),  b0 = pkbf(SV[2],SV[3]); \
            unsigned int c0 = pkbf(SV[4],SV[5]),  d0 = pkbf(SV[6],SV[7]); \
            unsigned int a1 = pkbf(SV[8],SV[9]),  b1 = pkbf(SV[10],SV[11]); \
            unsigned int c1 = pkbf(SV[12],SV[13]),d1 = pkbf(SV[14],SV[15]); \
            asm("v_permlane32_swap_b32 %0, %1" : "+v"(a0), "+v"(c0)); \
            asm("v_permlane32_swap_b32 %0, %1" : "+v"(b0), "+v"(d0)); \
            asm("v_permlane32_swap_b32 %0, %1" : "+v"(a1), "+v"(c1)); \
            asm("v_permlane32_swap_b32 %0, %1" : "+v"(b1), "+v"(d1)); \
            U8 u; \
            u.w[0] = a0; u.w[1] = b0; u.w[2] = c0; u.w[3] = d0; dA = u.v; \
            u.w[0] = a1; u.w[1] = b1; u.w[2] = c1; u.w[3] = d1; dB = u.v; \
        } while(0)
        MAKEPF(pf[0], pf[1], st0);
        MAKEPF(pf[2], pf[3], st1);
        #undef MAKEPF

        // ---- O^T += V^T * P ----
        __builtin_amdgcn_s_setprio(1);
        #pragma unroll
        for (int dt = 0; dt < 4; ++dt){
            const int rowv = (dt<<5) + lq;
            #pragma unroll
            for (int f = 0; f < 4; ++f){
                const int col = (((f<<1) + hi) ^ (lq & 7)) << 3;
                bf16x8 vf = *reinterpret_cast<const bf16x8*>(&Vbuf[(rowv<<6) + col]);
                oacc[dt] = __builtin_amdgcn_mfma_f32_32x32x16_bf16(vf, pf[f], oacc[dt], 0, 0, 0);
            }
        }
        __builtin_amdgcn_s_setprio(0);

        __syncthreads();
        buf ^= 1;
    }
    #undef STAGE

    // ---- epilogue: O^T -> per-wave LDS transpose (reusing smem) -> coalesced global ----
    const float rl = 1.0f / l_run;
    unsigned short* oL = smem + wave*(32*132);
    #pragma unroll
    for (int dt = 0; dt < 4; ++dt)
        #pragma unroll
        for (int g = 0; g < 4; ++g){
            u16x4 w = { f2b(oacc[dt][g*4+0]*rl), f2b(oacc[dt][g*4+1]*rl),
                        f2b(oacc[dt][g*4+2]*rl), f2b(oacc[dt][g*4+3]*rl) };
            *reinterpret_cast<u16x4*>(&oL[lq*132 + (dt<<5) + (hi<<2) + (g<<3)]) = w;
        }
    #pragma unroll
    for (int i = 0; i < 16; ++i){
        const int q = (i<<1) + hi;
        u16x4 w = *reinterpret_cast<const u16x4*>(&oL[q*132 + (lq<<2)]);
        *reinterpret_cast<u16x4*>(&aout[(size_t)(b*SEQ + q0w + q)*DIMS + h*HD + (lq<<2)]) = w;
    }
}

// ---------------- launcher ----------------

extern "C" void kernel_launch(void* const* d_in, const int* in_sizes, int n_in,
                              void* d_out, int out_size, void* d_ws, size_t ws_size,
                              hipStream_t stream)
{
    const float* x    = (const float*)d_in[0];
    const float* rope = (const float*)d_in[1];
    const float* wq   = (const float*)d_in[2];
    const float* wk   = (const float*)d_in[3];
    const float* wv   = (const float*)d_in[4];
    const float* wo   = (const float*)d_in[5];
    const float* bo   = (const float*)d_in[6];
    float* out = (float*)d_out;

    char* ws = (char*)d_ws;
    unsigned short* x_bf   = (unsigned short*)(ws + 0);            // 16.8 MB
    unsigned short* wqkv   = (unsigned short*)(ws + 16777216);     // 25.2 MB
    unsigned short* wo_bf  = (unsigned short*)(ws + 41943040);     // 8.4 MB
    float*          cos_t  = (float*)(ws + 50331648);              // 1 MB
    float*          sin_t  = (float*)(ws + 51380224);              // 1 MB
    unsigned short* qkv    = (unsigned short*)(ws + 52428800);     // 50.3 MB
    unsigned short* vt     = (unsigned short*)(ws + 16777216);     // alias wqkv
    unsigned short* a_out  = (unsigned short*)(ws + 0);            // alias x_bf

    // 1. fused prep: x->bf16, 4 weights->bf16, cos/sin
    k_prep<<<dim3(4096, 7), 256, 0, stream>>>(x, wq, wk, wv, wo, rope,
                                              x_bf, wqkv, wqkv + 4194304, wqkv + 8388608, wo_bf,
                                              cos_t, sin_t);

    // 2. QKV projection: m97 128^2 kernel, grid 32*48 = 1536
    k_gemm_bt<0><<<(MROWS/128)*(QKVN/128), 256, 0, stream>>>(x_bf, wqkv, qkv, nullptr, MROWS, QKVN, DIMS);

    // 3. fused K-rope (in place) + V transpose
    k_kropevt<<<4096, 256, 0, stream>>>(qkv, cos_t, sin_t, vt);

    // 4. attention (Q-rope in-register): 512 blocks = 2/CU x 256 CUs
    k_attn<<<dim3(SEQ/128, BATCH*HEADS), 256, 0, stream>>>(qkv, vt, cos_t, sin_t, a_out);

    // 5. output projection + bias
    k_gemm_bt<1><<<(MROWS/128)*(DIMS/128), 256, 0, stream>>>(a_out, wo_bf, out, bo, MROWS, DIMS, DIMS);
}